// Round 1
// baseline (249.688 us; speedup 1.0000x reference)
//
#include <hip/hip_runtime.h>
#include <math.h>

#define BB   4
#define CCH  256
#define KK   8
#define NPIX 16384
#define TILE 256
#define NBLK 64            // blocks per batch = NPIX/TILE
#define TEMP_INV 1.25f     // 1/0.8
#define EPSF 1e-6f

// ---------------------------------------------------------------------------
// Pass kernel: one fused distance->softmax->accumulate pass over feats.
// MODE 0: seeds (gproto = seed_w, + bias), also computes f_sq.
// MODE 1: cluster iteration (logits from -dist/TEMP).
// MODE 2: like 1, but also writes logits_map and probs(=assign) outputs.
// Grid: BB*NBLK blocks x 1024 threads. Each block owns TILE=256 pixels.
// Phase 1: thread (q=t>>8, p=t&255) covers channels [64q,64q+64) of pixel p.
// Phase 2: thread (qq=t>>8, ch=t&255) covers pixels [64qq,64qq+64) of channel ch.
// ---------------------------------------------------------------------------
template<int MODE>
__global__ __launch_bounds__(1024)
void skm_pass(const float* __restrict__ feats,
              const float* __restrict__ seed_w,
              const float* __restrict__ seed_b,
              const float* __restrict__ proto_ws,
              const float* __restrict__ psq_ws,
              float* __restrict__ fsq,
              float* __restrict__ part_num,
              float* __restrict__ part_den,
              float* __restrict__ logits_out,
              float* __restrict__ probs_out)
{
    __shared__ float cross_s[4][KK][TILE];   // 32 KB, reused for phase-2 acc
    __shared__ float w_s[KK][TILE];          // 8 KB softmax weights
    __shared__ float fs_s[4][TILE];          // 4 KB (MODE 0 only)
    __shared__ float pk_s[KK];               // bias (MODE 0) or p_sq

    const int t   = threadIdx.x;
    const int bid = blockIdx.x;
    const int b   = bid >> 6;                // /NBLK
    const int blk = bid & (NBLK - 1);
    const int n0  = blk * TILE;

    const float* __restrict__ gproto = (MODE == 0) ? seed_w : (proto_ws + b * KK * CCH);

    if (t < KK) pk_s[t] = (MODE == 0) ? seed_b[t] : psq_ws[b * KK + t];

    // ---- phase 1: cross[k][p] with 4-way channel split ----
    const int p  = t & (TILE - 1);
    const int q  = t >> 8;                   // 0..3
    const int c0 = q * 64;
    const float* fcol = feats + ((size_t)b * CCH) * NPIX + n0 + p;

    float cr[KK];
    #pragma unroll
    for (int k = 0; k < KK; ++k) cr[k] = 0.f;
    float fs = 0.f;

    #pragma unroll 8
    for (int cc = 0; cc < 64; ++cc) {
        const int c = c0 + cc;
        const float f = fcol[(size_t)c * NPIX];       // coalesced across lanes
        if (MODE == 0) fs += f * f;
        #pragma unroll
        for (int k = 0; k < KK; ++k)
            cr[k] = fmaf(gproto[k * CCH + c], f, cr[k]);  // uniform addr -> s_load
    }
    #pragma unroll
    for (int k = 0; k < KK; ++k) cross_s[q][k][p] = cr[k];
    if (MODE == 0) fs_s[q][p] = fs;
    __syncthreads();

    // ---- softmax over k, by threads 0..255 (one per pixel) ----
    if (t < TILE) {
        float lg[KK];
        #pragma unroll
        for (int k = 0; k < KK; ++k)
            lg[k] = cross_s[0][k][t] + cross_s[1][k][t] + cross_s[2][k][t] + cross_s[3][k][t];
        if (MODE == 0) {
            const float fv = fs_s[0][t] + fs_s[1][t] + fs_s[2][t] + fs_s[3][t];
            fsq[b * NPIX + n0 + t] = fv;
            #pragma unroll
            for (int k = 0; k < KK; ++k) lg[k] += pk_s[k];
        } else {
            const float fv = fsq[b * NPIX + n0 + t];
            #pragma unroll
            for (int k = 0; k < KK; ++k)
                lg[k] = (2.f * lg[k] - fv - pk_s[k]) * TEMP_INV;   // -dist/TEMP
        }
        float m = lg[0];
        #pragma unroll
        for (int k = 1; k < KK; ++k) m = fmaxf(m, lg[k]);
        float e[KK], ssum = 0.f;
        #pragma unroll
        for (int k = 0; k < KK; ++k) { e[k] = expf(lg[k] - m); ssum += e[k]; }
        const float inv = 1.f / ssum;
        #pragma unroll
        for (int k = 0; k < KK; ++k) {
            const float wv = e[k] * inv;
            w_s[k][t] = wv;
            if (MODE == 2) {
                logits_out[(b * KK + k) * NPIX + n0 + t] = lg[k];
                probs_out [(b * KK + k) * NPIX + n0 + t] = wv;
            }
        }
    }
    __syncthreads();

    // ---- per-block denominator partials (threads 0..255, 32 lanes per k) ----
    if (t < 256) {
        const int k = t >> 5, lane = t & 31;
        float s = 0.f;
        #pragma unroll
        for (int j = 0; j < 8; ++j) s += w_s[k][lane * 8 + j];
        #pragma unroll
        for (int mm = 16; mm >= 1; mm >>= 1) s += __shfl_xor(s, mm, 64);
        if (lane == 0) part_den[(b * NBLK + blk) * KK + k] = s;
    }

    // ---- phase 2: num[k][ch] partials; thread owns channel ch, 64 pixels ----
    const int ch = t & (CCH - 1);
    const int qq = t >> 8;
    const int p0 = qq * 64;
    const float4* frow = (const float4*)(feats + ((size_t)b * CCH + ch) * NPIX + n0 + p0);
    float4 fv4[16];
    #pragma unroll
    for (int j = 0; j < 16; ++j) fv4[j] = frow[j];    // L2/L3-resident re-read
    float acc[KK];
    #pragma unroll
    for (int k = 0; k < KK; ++k) acc[k] = 0.f;
    #pragma unroll 4
    for (int j = 0; j < 16; ++j) {
        #pragma unroll
        for (int k = 0; k < KK; ++k) {
            const float4 wv = ((const float4*)&w_s[k][p0])[j];  // broadcast b128
            acc[k] = fmaf(wv.x, fv4[j].x, acc[k]);
            acc[k] = fmaf(wv.y, fv4[j].y, acc[k]);
            acc[k] = fmaf(wv.z, fv4[j].z, acc[k]);
            acc[k] = fmaf(wv.w, fv4[j].w, acc[k]);
        }
    }
    __syncthreads();
    #pragma unroll
    for (int k = 0; k < KK; ++k) cross_s[qq][k][ch] = acc[k];
    __syncthreads();
    for (int u = t; u < KK * CCH; u += 1024) {
        const int k = u >> 8, c2 = u & (CCH - 1);
        const float s = cross_s[0][k][c2] + cross_s[1][k][c2]
                      + cross_s[2][k][c2] + cross_s[3][k][c2];
        part_num[(((size_t)b * NBLK + blk) * KK + k) * CCH + c2] = s;
    }
}

// ---------------------------------------------------------------------------
// Reduce: sum 64 block-partials -> proto_ws (= num/(den+eps)), p_sq.
// Grid: 32 blocks (b,k) x 256 threads (one per channel). Deterministic order.
// ---------------------------------------------------------------------------
__global__ __launch_bounds__(256)
void skm_reduce(const float* __restrict__ part_num,
                const float* __restrict__ part_den,
                float* __restrict__ proto_ws,
                float* __restrict__ psq_ws,
                float* __restrict__ proto_out)
{
    const int bid = blockIdx.x;          // 0..31
    const int b = bid >> 3, k = bid & 7;
    const int t = threadIdx.x;

    float num = 0.f;
    #pragma unroll 8
    for (int j = 0; j < NBLK; ++j)
        num += part_num[(((size_t)b * NBLK + j) * KK + k) * CCH + t];

    __shared__ float den_s;
    __shared__ float red[256];
    if (t < 64) {
        float d = part_den[(b * NBLK + t) * KK + k];
        #pragma unroll
        for (int mm = 32; mm >= 1; mm >>= 1) d += __shfl_xor(d, mm, 64);
        if (t == 0) den_s = d + EPSF;
    }
    __syncthreads();
    const float pv = num / den_s;
    proto_ws[(b * KK + k) * CCH + t] = pv;
    if (proto_out) proto_out[(b * KK + k) * CCH + t] = pv;

    red[t] = pv * pv;
    __syncthreads();
    if (t < 128) red[t] += red[t + 128];
    __syncthreads();
    if (t < 64) {
        float v = red[t] + red[t + 64];
        #pragma unroll
        for (int mm = 32; mm >= 1; mm >>= 1) v += __shfl_xor(v, mm, 64);
        if (t == 0) psq_ws[b * KK + k] = v;
    }
}

// ---------------------------------------------------------------------------
// Bilinear x4 upsample, half-pixel, edge clamp (== jax linear resize here).
// One thread = 4 horizontal outputs (one float4 store). Grid 8192x256.
// ---------------------------------------------------------------------------
__global__ __launch_bounds__(256)
void skm_upsample(const float* __restrict__ probs, float* __restrict__ outp)
{
    const int gid = blockIdx.x * 256 + threadIdx.x;    // 0..2097151
    const int jb = gid & 127;
    const int i  = (gid >> 7) & 511;
    const int bk = gid >> 16;                          // b*8 + k
    const float* src = probs + (size_t)bk * NPIX;

    const float y   = i * 0.25f - 0.375f;
    const float y0f = floorf(y);
    const float fy  = y - y0f;
    const int   y0  = (int)y0f;
    const int ya = min(max(y0, 0), 127);
    const int yb = min(max(y0 + 1, 0), 127);
    const int xm = max(jb - 1, 0);
    const int xp = min(jb + 1, 127);

    const float* r0 = src + ya * 128;
    const float* r1 = src + yb * 128;
    const float wy0 = 1.f - fy;
    const float am = r0[xm] * wy0 + r1[xm] * fy;
    const float ac = r0[jb] * wy0 + r1[jb] * fy;
    const float ap = r0[xp] * wy0 + r1[xp] * fy;

    float4 o;
    o.x = 0.375f * am + 0.625f * ac;   // j = 4jb+0, x = jb-0.375
    o.y = 0.125f * am + 0.875f * ac;   // j = 4jb+1, x = jb-0.125
    o.z = 0.875f * ac + 0.125f * ap;   // j = 4jb+2, x = jb+0.125
    o.w = 0.625f * ac + 0.375f * ap;   // j = 4jb+3, x = jb+0.375
    ((float4*)outp)[gid] = o;
}

// ---------------------------------------------------------------------------
extern "C" void kernel_launch(void* const* d_in, const int* in_sizes, int n_in,
                              void* d_out, int out_size, void* d_ws, size_t ws_size,
                              hipStream_t stream)
{
    const float* feats  = (const float*)d_in[0];   // [4][256][16384]
    const float* seed_w = (const float*)d_in[1];   // [16][256] (use first 8 rows)
    const float* seed_b = (const float*)d_in[2];   // [16]
    // d_in[3]: k (int) — fixed at 8 by setup_inputs; grid shapes hardcoded.

    float* out        = (float*)d_out;
    float* probs_full = out;                        // 4*8*512*512 = 8388608
    float* proto_out  = out + 8388608;              // 4*8*256     = 8192
    float* logits_out = out + 8388608 + 8192;       // 4*8*128*128 = 524288

    float* ws       = (float*)d_ws;
    float* fsq      = ws;                           // 65536
    float* part_num = ws + 65536;                   // 4*64*8*256 = 524288
    float* part_den = part_num + 524288;            // 4*64*8 = 2048
    float* proto_ws = part_den + 2048;              // 8192
    float* psq_ws   = proto_ws + 8192;              // 32
    float* probs_ws = psq_ws + 32;                  // 524288  (total ~4.5 MB)

    const dim3 pg(BB * NBLK), pb(1024);
    const dim3 rg(32), rb(256);

    // seed pass + initial proto
    skm_pass<0><<<pg, pb, 0, stream>>>(feats, seed_w, seed_b, proto_ws, psq_ws,
                                       fsq, part_num, part_den, nullptr, nullptr);
    skm_reduce<<<rg, rb, 0, stream>>>(part_num, part_den, proto_ws, psq_ws, nullptr);
    // cluster iterations 1,2
    skm_pass<1><<<pg, pb, 0, stream>>>(feats, seed_w, seed_b, proto_ws, psq_ws,
                                       fsq, part_num, part_den, nullptr, nullptr);
    skm_reduce<<<rg, rb, 0, stream>>>(part_num, part_den, proto_ws, psq_ws, nullptr);
    skm_pass<1><<<pg, pb, 0, stream>>>(feats, seed_w, seed_b, proto_ws, psq_ws,
                                       fsq, part_num, part_den, nullptr, nullptr);
    skm_reduce<<<rg, rb, 0, stream>>>(part_num, part_den, proto_ws, psq_ws, nullptr);
    // iteration 3: emit logits_map + probs(=assign), final proto -> d_out
    skm_pass<2><<<pg, pb, 0, stream>>>(feats, seed_w, seed_b, proto_ws, psq_ws,
                                       fsq, part_num, part_den, logits_out, probs_ws);
    skm_reduce<<<rg, rb, 0, stream>>>(part_num, part_den, proto_ws, psq_ws, proto_out);
    // upsample x4
    skm_upsample<<<dim3(8192), dim3(256), 0, stream>>>(probs_ws, probs_full);
}

// Round 2
// 137.516 us; speedup vs baseline: 1.8157x; 1.8157x over previous
//
#include <hip/hip_runtime.h>
#include <math.h>

#define BB   4
#define CCH  256
#define KK   8
#define NPIX 16384
#define TILE 128
#define NBLK 128           // blocks per batch = NPIX/TILE
#define TEMP_INV 1.25f     // 1/0.8
#define EPSF 1e-6f

// ---------------------------------------------------------------------------
// Pass kernel: fused distance -> softmax -> accumulate, one pass over feats.
// MODE 0: seeds (proto_t = transposed seed_w, + bias), also computes f_sq.
// MODE 1: cluster iteration. MODE 2: iteration + emit logits/probs.
// Grid: BB*NBLK = 512 blocks x 1024 threads (2 blocks/CU -> 32 waves/CU).
// Phase 1: wave g in [0,16) owns 16 channels; lane d owns pixel duo 2d,2d+1.
//          proto_t[c][k] read via uniform s_load (readfirstlane on g).
// Phase 2: thread (c = t&255, h = t>>8) re-reads 32 px of channel c (L2-hot).
// ---------------------------------------------------------------------------
template<int MODE>
__global__ __launch_bounds__(1024, 8)
void skm_pass(const float* __restrict__ feats,
              const float* __restrict__ proto_t,   // [256][8] (MODE0: seed_t) or [b][256][8]
              const float* __restrict__ seed_b,
              const float* __restrict__ psq_ws,
              float* __restrict__ fsq,
              float* __restrict__ part_num,
              float* __restrict__ part_den,
              float* __restrict__ logits_out,
              float* __restrict__ probs_out)
{
    __shared__ float cross_s[16][KK][132];   // 67584 B (padded: softmax reads conflict-free)
    __shared__ float w_s[KK][132];           // 4224 B  (rows 16B-aligned: 132*4=528)
    __shared__ float aux_s[16][128];         // 8192 B: fs partials (MODE0) / lg staging (MODE2)

    const int t   = threadIdx.x;
    const int bid = blockIdx.x;
    const int b   = bid >> 7;                // /NBLK
    const int blk = bid & (NBLK - 1);
    const int n0  = blk * TILE;

    // ---- phase 1: cross[k][p], 16 channel-groups x 64 pixel-duos ----
    const int d  = t & 63;
    const int g  = t >> 6;                               // wave id = channel group
    const int c0 = __builtin_amdgcn_readfirstlane(g) * 16;   // SGPR -> s_load of proto
    const float* pt  = proto_t + (MODE == 0 ? 0 : (size_t)b * CCH * KK) + (size_t)c0 * KK;
    const float* f2p = feats + (size_t)b * CCH * NPIX + (size_t)c0 * NPIX + n0 + 2 * d;

    float cr0[KK], cr1[KK];
    #pragma unroll
    for (int k = 0; k < KK; ++k) { cr0[k] = 0.f; cr1[k] = 0.f; }
    float fs0 = 0.f, fs1 = 0.f;

    #pragma unroll 8
    for (int cc = 0; cc < 16; ++cc) {
        const float2 f = *(const float2*)(f2p + (size_t)cc * NPIX);  // 512 B/wave coalesced
        if (MODE == 0) { fs0 = fmaf(f.x, f.x, fs0); fs1 = fmaf(f.y, f.y, fs1); }
        const float* pr = pt + cc * KK;                  // wave-uniform -> s_load
        #pragma unroll
        for (int k = 0; k < KK; ++k) {
            cr0[k] = fmaf(pr[k], f.x, cr0[k]);
            cr1[k] = fmaf(pr[k], f.y, cr1[k]);
        }
    }
    #pragma unroll
    for (int k = 0; k < KK; ++k) {
        float2 v; v.x = cr0[k]; v.y = cr1[k];
        *(float2*)&cross_s[g][k][2 * d] = v;
    }
    if (MODE == 0) { aux_s[g][2 * d] = fs0; aux_s[g][2 * d + 1] = fs1; }
    __syncthreads();

    // ---- softmax over k: thread = (pixel p, cluster k), shuffle over k-octet ----
    {
        const int p = t >> 3, k = t & 7;
        float lg = 0.f;
        #pragma unroll
        for (int gg = 0; gg < 16; ++gg) lg += cross_s[gg][k][p];
        if (MODE == 0) {
            lg += seed_b[k];
            if (k == 0) {
                float fv = 0.f;
                #pragma unroll
                for (int gg = 0; gg < 16; ++gg) fv += aux_s[gg][p];
                fsq[b * NPIX + n0 + p] = fv;
            }
        } else {
            const float fv = fsq[b * NPIX + n0 + p];
            const float pk = psq_ws[b * KK + k];
            lg = (2.f * lg - fv - pk) * TEMP_INV;        // -dist/TEMP
        }
        float m = lg;
        m = fmaxf(m, __shfl_xor(m, 1, 64));
        m = fmaxf(m, __shfl_xor(m, 2, 64));
        m = fmaxf(m, __shfl_xor(m, 4, 64));
        float e = expf(lg - m);
        float ssum = e;
        ssum += __shfl_xor(ssum, 1, 64);
        ssum += __shfl_xor(ssum, 2, 64);
        ssum += __shfl_xor(ssum, 4, 64);
        const float wv = e / ssum;
        w_s[k][p] = wv;
        if (MODE == 2) ((float*)aux_s)[k * 128 + p] = lg;
    }
    __syncthreads();

    // ---- MODE 2: coalesced logits/probs writes from LDS staging ----
    if (MODE == 2) {
        const int k2 = t >> 7, p2 = t & 127;
        logits_out[((size_t)b * KK + k2) * NPIX + n0 + p2] = ((float*)aux_s)[k2 * 128 + p2];
        probs_out [((size_t)b * KK + k2) * NPIX + n0 + p2] = w_s[k2][p2];
    }

    // ---- per-block denominator partials ----
    if (t < 256) {
        const int kk = t >> 5, l = t & 31;
        float s = w_s[kk][l * 4] + w_s[kk][l * 4 + 1] + w_s[kk][l * 4 + 2] + w_s[kk][l * 4 + 3];
        s += __shfl_xor(s, 16, 64);
        s += __shfl_xor(s, 8, 64);
        s += __shfl_xor(s, 4, 64);
        s += __shfl_xor(s, 2, 64);
        s += __shfl_xor(s, 1, 64);
        if (l == 0) part_den[(b * NBLK + blk) * KK + kk] = s;
    }

    // ---- phase 2: num[k][c] partials; thread = (channel c, pixel-quarter h) ----
    {
        const int c = t & (CCH - 1);
        const int h = t >> 8;                            // 0..3, 32 px each
        const float4* frow = (const float4*)(feats + ((size_t)b * CCH + c) * NPIX + n0 + 32 * h);
        float acc[KK];
        #pragma unroll
        for (int k = 0; k < KK; ++k) acc[k] = 0.f;
        #pragma unroll
        for (int j = 0; j < 8; ++j) {
            const float4 f4 = frow[j];                   // L2-hot re-read
            #pragma unroll
            for (int k = 0; k < KK; ++k) {
                const float4 w4 = *(const float4*)&w_s[k][32 * h + 4 * j];  // wave-broadcast
                acc[k] = fmaf(f4.w, w4.w, fmaf(f4.z, w4.z,
                         fmaf(f4.y, w4.y, fmaf(f4.x, w4.x, acc[k]))));
            }
        }
        float (*acc_s)[KK][CCH] = (float (*)[KK][CCH])cross_s;   // reuse (all reads done)
        #pragma unroll
        for (int k = 0; k < KK; ++k) acc_s[h][k][c] = acc[k];
        __syncthreads();
        #pragma unroll
        for (int u = t; u < KK * CCH; u += 1024) {
            const int k = u >> 8, c2 = u & (CCH - 1);
            const float s = acc_s[0][k][c2] + acc_s[1][k][c2]
                          + acc_s[2][k][c2] + acc_s[3][k][c2];
            part_num[(((size_t)b * NBLK + blk) * KK + k) * CCH + c2] = s;
        }
    }
}

// ---------------------------------------------------------------------------
// Reduce: sum 128 block-partials -> proto (transposed for next pass), p_sq.
// Grid: 32 blocks (b,k) x 1024 threads (4-way j-split per channel).
// ---------------------------------------------------------------------------
__global__ __launch_bounds__(1024)
void skm_reduce(const float* __restrict__ part_num,
                const float* __restrict__ part_den,
                float* __restrict__ proto_t,
                float* __restrict__ psq_ws,
                float* __restrict__ proto_out)
{
    const int bid = blockIdx.x;          // 0..31
    const int b = bid >> 3, k = bid & 7;
    const int t = threadIdx.x;
    const int jj = t >> 8, c = t & 255;

    float s = 0.f;
    #pragma unroll 8
    for (int j = 0; j < 32; ++j)
        s += part_num[(((size_t)b * NBLK + jj * 32 + j) * KK + k) * CCH + c];

    __shared__ float red_s[4][CCH];
    __shared__ float den_s[2];
    __shared__ float red2[CCH];
    red_s[jj][c] = s;

    if (t < 128) {
        float dv = part_den[(b * NBLK + t) * KK + k];
        #pragma unroll
        for (int m = 32; m >= 1; m >>= 1) dv += __shfl_xor(dv, m, 64);
        if ((t & 63) == 0) den_s[t >> 6] = dv;
    }
    __syncthreads();

    if (t < 256) {
        const float den = den_s[0] + den_s[1] + EPSF;
        const float pv = (red_s[0][t] + red_s[1][t] + red_s[2][t] + red_s[3][t]) / den;
        proto_t[((size_t)b * CCH + t) * KK + k] = pv;      // transposed for s_load in pass
        if (proto_out) proto_out[(b * KK + k) * CCH + t] = pv;
        red2[t] = pv * pv;
    }
    __syncthreads();
    if (t < 64) {
        float v = red2[t] + red2[t + 64] + red2[t + 128] + red2[t + 192];
        #pragma unroll
        for (int m = 32; m >= 1; m >>= 1) v += __shfl_xor(v, m, 64);
        if (t == 0) psq_ws[b * KK + k] = v;
    }
}

// ---------------------------------------------------------------------------
// Prep: transpose seed_w[k][c] (first 8 rows) -> seed_t[c][k].
// ---------------------------------------------------------------------------
__global__ __launch_bounds__(256)
void skm_prep(const float* __restrict__ seed_w, float* __restrict__ seed_t)
{
    const int c = threadIdx.x;
    #pragma unroll
    for (int k = 0; k < KK; ++k) seed_t[c * KK + k] = seed_w[k * CCH + c];
}

// ---------------------------------------------------------------------------
// Bilinear x4 upsample, half-pixel, edge clamp (== jax linear resize here).
// ---------------------------------------------------------------------------
__global__ __launch_bounds__(256)
void skm_upsample(const float* __restrict__ probs, float* __restrict__ outp)
{
    const int gid = blockIdx.x * 256 + threadIdx.x;    // 0..2097151
    const int jb = gid & 127;
    const int i  = (gid >> 7) & 511;
    const int bk = gid >> 16;                          // b*8 + k
    const float* src = probs + (size_t)bk * NPIX;

    const float y   = i * 0.25f - 0.375f;
    const float y0f = floorf(y);
    const float fy  = y - y0f;
    const int   y0  = (int)y0f;
    const int ya = min(max(y0, 0), 127);
    const int yb = min(max(y0 + 1, 0), 127);
    const int xm = max(jb - 1, 0);
    const int xp = min(jb + 1, 127);

    const float* r0 = src + ya * 128;
    const float* r1 = src + yb * 128;
    const float wy0 = 1.f - fy;
    const float am = r0[xm] * wy0 + r1[xm] * fy;
    const float ac = r0[jb] * wy0 + r1[jb] * fy;
    const float ap = r0[xp] * wy0 + r1[xp] * fy;

    float4 o;
    o.x = 0.375f * am + 0.625f * ac;
    o.y = 0.125f * am + 0.875f * ac;
    o.z = 0.875f * ac + 0.125f * ap;
    o.w = 0.625f * ac + 0.375f * ap;
    ((float4*)outp)[gid] = o;
}

// ---------------------------------------------------------------------------
extern "C" void kernel_launch(void* const* d_in, const int* in_sizes, int n_in,
                              void* d_out, int out_size, void* d_ws, size_t ws_size,
                              hipStream_t stream)
{
    const float* feats  = (const float*)d_in[0];   // [4][256][16384]
    const float* seed_w = (const float*)d_in[1];   // [16][256] (use first 8 rows)
    const float* seed_b = (const float*)d_in[2];   // [16]
    // d_in[3]: k (int) — fixed at 8 by setup_inputs; grid shapes hardcoded.

    float* out        = (float*)d_out;
    float* probs_full = out;                        // 4*8*512*512 = 8388608
    float* proto_out  = out + 8388608;              // 4*8*256     = 8192
    float* logits_out = out + 8388608 + 8192;       // 4*8*128*128 = 524288

    // part_num (4 MB) lives in the probs_full region of d_out: it is fully
    // consumed by skm_reduce before skm_upsample overwrites the region last.
    float* part_num = probs_full;                   // 4*128*8*256 = 1048576 floats

    float* ws       = (float*)d_ws;
    float* fsq      = ws;                           // 65536
    float* part_den = ws + 65536;                   // 4*128*8 = 4096
    float* seed_t   = part_den + 4096;              // 2048
    float* proto_t  = seed_t + 2048;                // 4*256*8 = 8192
    float* psq_ws   = proto_t + 8192;               // 32
    float* probs_ws = psq_ws + 32;                  // 524288  (total ~2.4 MB)

    const dim3 pg(BB * NBLK), pb(1024);
    const dim3 rg(32), rb(1024);

    skm_prep<<<dim3(1), dim3(256), 0, stream>>>(seed_w, seed_t);

    // seed pass + initial proto
    skm_pass<0><<<pg, pb, 0, stream>>>(feats, seed_t, seed_b, psq_ws,
                                       fsq, part_num, part_den, nullptr, nullptr);
    skm_reduce<<<rg, rb, 0, stream>>>(part_num, part_den, proto_t, psq_ws, nullptr);
    // cluster iterations 1,2
    skm_pass<1><<<pg, pb, 0, stream>>>(feats, proto_t, seed_b, psq_ws,
                                       fsq, part_num, part_den, nullptr, nullptr);
    skm_reduce<<<rg, rb, 0, stream>>>(part_num, part_den, proto_t, psq_ws, nullptr);
    skm_pass<1><<<pg, pb, 0, stream>>>(feats, proto_t, seed_b, psq_ws,
                                       fsq, part_num, part_den, nullptr, nullptr);
    skm_reduce<<<rg, rb, 0, stream>>>(part_num, part_den, proto_t, psq_ws, nullptr);
    // iteration 3: emit logits_map + probs(=assign), final proto -> d_out
    skm_pass<2><<<pg, pb, 0, stream>>>(feats, proto_t, seed_b, psq_ws,
                                       fsq, part_num, part_den, logits_out, probs_ws);
    skm_reduce<<<rg, rb, 0, stream>>>(part_num, part_den, proto_t, psq_ws, proto_out);
    // upsample x4 (overwrites part_num region with final probs)
    skm_upsample<<<dim3(8192), dim3(256), 0, stream>>>(probs_ws, probs_full);
}

// Round 3
// 109.553 us; speedup vs baseline: 2.2792x; 1.2552x over previous
//
#include <hip/hip_runtime.h>
#include <hip/hip_bf16.h>
#include <math.h>

#define BB   4
#define CCH  256
#define KK   8
#define NPIX 16384
#define TILE 64
#define NBLK 256           // blocks per batch = NPIX/TILE
#define TEMP_INV 1.25f     // 1/0.8
#define EPSF 1e-6f

__device__ __forceinline__ float bf_lo(unsigned int u) { return __uint_as_float(u << 16); }
__device__ __forceinline__ float bf_hi(unsigned int u) { return __uint_as_float(u & 0xffff0000u); }

// ---------------------------------------------------------------------------
// Pass kernel: fused distance -> softmax -> accumulate; feats read from
// global ONCE (phase 1, coalesced); phase 2 re-reads a bf16 LDS copy.
// MODE 0: seeds (s_load seed_w transposed) + bias, also computes f_sq.
// MODE 1: cluster iteration. MODE 2: iteration + emit logits/probs.
// Grid: BB*NBLK = 1024 blocks x 512 threads; ~52.6 KB LDS -> 3 blocks/CU.
// Phase 1: wave g in [0,8) owns 32 channels; lane = pixel. proto via s_load.
// bf16 tile swizzle: word w of row c stored at w ^ ((c&15)<<1)  (pair-
// preserving XOR -> phase-2 b64 column reads are bank-optimal).
// Phase 2: thread (c = t&255, h = t>>8) covers 32 px of channel c from LDS.
// ---------------------------------------------------------------------------
template<int MODE>
__global__ __launch_bounds__(512, 6)
void skm_pass(const float* __restrict__ feats,
              const float* __restrict__ seed_w,
              const float* __restrict__ seed_b,
              const float* __restrict__ proto_t,   // [b][256][8]
              const float* __restrict__ psq_ws,
              float* __restrict__ fsq,
              float* __restrict__ part_num,
              float* __restrict__ part_den,
              float* __restrict__ logits_out,
              float* __restrict__ probs_out)
{
    __shared__ unsigned int fb_s[CCH][32];   // 32 KB: bf16 feats tile, swizzled
    __shared__ float cross_s[8][KK][66];     // 16.5 KB (pad 66: softmax ~2-way)
    __shared__ float w_s[KK][68];            // 2.1 KB (rows 16B-aligned)
    __shared__ float aux_s[8][TILE];         // 2 KB: fs partials (M0) / lg (M2)

    const int t   = threadIdx.x;
    const int bid = blockIdx.x;
    const int b   = bid >> 8;
    const int blk = bid & 255;
    const int n0  = blk * TILE;

    // ---- phase 1: cross[k][p]; 8 waves = 8 channel-groups of 32 ----
    const int p  = t & 63;                               // pixel (lane)
    const int g  = t >> 6;                               // wave = channel group
    const int c0 = __builtin_amdgcn_readfirstlane(g) * 32;
    const float* fcol = feats + (size_t)b * CCH * NPIX + (size_t)c0 * NPIX + n0 + p;
    const float* pt   = proto_t + (size_t)b * CCH * KK + (size_t)c0 * KK;

    float cr[KK];
    #pragma unroll
    for (int k = 0; k < KK; ++k) cr[k] = 0.f;
    float fs = 0.f;

    #pragma unroll 8
    for (int cc = 0; cc < 32; ++cc) {
        const float f = fcol[(size_t)cc * NPIX];         // coalesced 256B/wave
        if (MODE == 0) fs = fmaf(f, f, fs);
        const int c  = c0 + cc;
        const int wp = (p >> 1) ^ ((c & 15) << 1);       // swizzled word
        ((__hip_bfloat16*)fb_s)[(c << 6) + (wp << 1) + (p & 1)] = __float2bfloat16(f);
        if (MODE == 0) {
            #pragma unroll
            for (int k = 0; k < KK; ++k)
                cr[k] = fmaf(seed_w[k * CCH + c], f, cr[k]);   // uniform -> s_load
        } else {
            const float* pr = pt + cc * KK;              // uniform -> s_load x8
            #pragma unroll
            for (int k = 0; k < KK; ++k)
                cr[k] = fmaf(pr[k], f, cr[k]);
        }
    }
    #pragma unroll
    for (int k = 0; k < KK; ++k) cross_s[g][k][p] = cr[k];
    if (MODE == 0) aux_s[g][p] = fs;
    __syncthreads();

    // ---- softmax over k: thread = (pixel pp, cluster k), shuffle in octet ----
    {
        const int pp = t >> 3, k = t & 7;
        float lg = 0.f;
        #pragma unroll
        for (int gg = 0; gg < 8; ++gg) lg += cross_s[gg][k][pp];
        if (MODE == 0) {
            lg += seed_b[k];
            if (k == 0) {
                float fv = 0.f;
                #pragma unroll
                for (int gg = 0; gg < 8; ++gg) fv += aux_s[gg][pp];
                fsq[b * NPIX + n0 + pp] = fv;
            }
        } else {
            const float fv = fsq[b * NPIX + n0 + pp];
            const float pk = psq_ws[b * KK + k];
            lg = (2.f * lg - fv - pk) * TEMP_INV;        // -dist/TEMP
        }
        float m = lg;
        m = fmaxf(m, __shfl_xor(m, 1, 64));
        m = fmaxf(m, __shfl_xor(m, 2, 64));
        m = fmaxf(m, __shfl_xor(m, 4, 64));
        const float e = expf(lg - m);
        float ssum = e;
        ssum += __shfl_xor(ssum, 1, 64);
        ssum += __shfl_xor(ssum, 2, 64);
        ssum += __shfl_xor(ssum, 4, 64);
        const float wv = e / ssum;
        w_s[k][pp] = wv;
        if (MODE == 2) aux_s[k][pp] = lg;                // lg staging (no fs in M2)
    }
    __syncthreads();

    // ---- MODE 2: coalesced logits/probs writes ----
    if (MODE == 2) {
        const int k2 = t >> 6, p2 = t & 63;
        logits_out[((size_t)b * KK + k2) * NPIX + n0 + p2] = aux_s[k2][p2];
        probs_out [((size_t)b * KK + k2) * NPIX + n0 + p2] = w_s[k2][p2];
    }

    // ---- per-block denominator partials ----
    if (t < 256) {
        const int kk = t >> 5, l = t & 31;
        float s = w_s[kk][2 * l] + w_s[kk][2 * l + 1];
        s += __shfl_xor(s, 16, 64);
        s += __shfl_xor(s, 8, 64);
        s += __shfl_xor(s, 4, 64);
        s += __shfl_xor(s, 2, 64);
        s += __shfl_xor(s, 1, 64);
        if (l == 0) part_den[(b * NBLK + blk) * KK + kk] = s;
    }

    // ---- phase 2: num[k][c] from bf16 LDS tile ----
    {
        const int c = t & 255, h = t >> 8;               // 32 px per thread
        const int s2 = (c & 15) << 1;
        const uint2* row2 = (const uint2*)fb_s[c];
        float acc[KK];
        #pragma unroll
        for (int k = 0; k < KK; ++k) acc[k] = 0.f;
        #pragma unroll
        for (int j = 0; j < 8; ++j) {
            const uint2 u = row2[((16 * h + 2 * j) ^ s2) >> 1];   // bank-optimal b64
            const float f0 = bf_lo(u.x), f1 = bf_hi(u.x);
            const float f2 = bf_lo(u.y), f3 = bf_hi(u.y);
            const int px = 32 * h + 4 * j;
            #pragma unroll
            for (int k = 0; k < KK; ++k) {
                const float4 w4 = *(const float4*)&w_s[k][px];    // broadcast b128
                acc[k] = fmaf(f3, w4.w, fmaf(f2, w4.z,
                         fmaf(f1, w4.y, fmaf(f0, w4.x, acc[k]))));
            }
        }
        float (*acc_s)[KK][CCH] = (float (*)[KK][CCH])cross_s;   // reuse (16 KB)
        #pragma unroll
        for (int k = 0; k < KK; ++k) acc_s[h][k][c] = acc[k];
        __syncthreads();
        #pragma unroll
        for (int u2 = t; u2 < KK * CCH; u2 += 512) {
            const int k = u2 >> 8, c2 = u2 & 255;
            part_num[(((size_t)b * NBLK + blk) * KK + k) * CCH + c2] =
                acc_s[0][k][c2] + acc_s[1][k][c2];
        }
    }
}

// ---------------------------------------------------------------------------
// Reduce: sum 256 block-partials -> proto_t (transposed), p_sq.
// Grid: 32 blocks (b,k) x 1024 threads (4-way j-split per channel).
// ---------------------------------------------------------------------------
__global__ __launch_bounds__(1024)
void skm_reduce(const float* __restrict__ part_num,
                const float* __restrict__ part_den,
                float* __restrict__ proto_t,
                float* __restrict__ psq_ws,
                float* __restrict__ proto_out)
{
    const int bid = blockIdx.x;          // 0..31
    const int b = bid >> 3, k = bid & 7;
    const int t = threadIdx.x;
    const int jj = t >> 8, c = t & 255;

    float s = 0.f;
    #pragma unroll 8
    for (int j = 0; j < 64; ++j)
        s += part_num[(((size_t)b * NBLK + jj * 64 + j) * KK + k) * CCH + c];

    __shared__ float red_s[4][CCH];
    __shared__ float den4[4];
    __shared__ float red2[CCH];
    red_s[jj][c] = s;

    if (t < 256) {
        float dv = part_den[(b * NBLK + t) * KK + k];
        dv += __shfl_xor(dv, 32, 64);
        dv += __shfl_xor(dv, 16, 64);
        dv += __shfl_xor(dv, 8, 64);
        dv += __shfl_xor(dv, 4, 64);
        dv += __shfl_xor(dv, 2, 64);
        dv += __shfl_xor(dv, 1, 64);
        if ((t & 63) == 0) den4[t >> 6] = dv;
    }
    __syncthreads();

    if (t < 256) {
        const float den = den4[0] + den4[1] + den4[2] + den4[3] + EPSF;
        const float pv = (red_s[0][t] + red_s[1][t] + red_s[2][t] + red_s[3][t]) / den;
        proto_t[((size_t)b * CCH + t) * KK + k] = pv;      // for s_load in pass
        if (proto_out) proto_out[(b * KK + k) * CCH + t] = pv;
        red2[t] = pv * pv;
    }
    __syncthreads();
    if (t < 64) {
        float v = red2[t] + red2[t + 64] + red2[t + 128] + red2[t + 192];
        v += __shfl_xor(v, 32, 64);
        v += __shfl_xor(v, 16, 64);
        v += __shfl_xor(v, 8, 64);
        v += __shfl_xor(v, 4, 64);
        v += __shfl_xor(v, 2, 64);
        v += __shfl_xor(v, 1, 64);
        if (t == 0) psq_ws[b * KK + k] = v;
    }
}

// ---------------------------------------------------------------------------
// Bilinear x4 upsample, half-pixel, edge clamp (== jax linear resize here).
// ---------------------------------------------------------------------------
__global__ __launch_bounds__(256)
void skm_upsample(const float* __restrict__ probs, float* __restrict__ outp)
{
    const int gid = blockIdx.x * 256 + threadIdx.x;    // 0..2097151
    const int jb = gid & 127;
    const int i  = (gid >> 7) & 511;
    const int bk = gid >> 16;                          // b*8 + k
    const float* src = probs + (size_t)bk * NPIX;

    const float y   = i * 0.25f - 0.375f;
    const float y0f = floorf(y);
    const float fy  = y - y0f;
    const int   y0  = (int)y0f;
    const int ya = min(max(y0, 0), 127);
    const int yb = min(max(y0 + 1, 0), 127);
    const int xm = max(jb - 1, 0);
    const int xp = min(jb + 1, 127);

    const float* r0 = src + ya * 128;
    const float* r1 = src + yb * 128;
    const float wy0 = 1.f - fy;
    const float am = r0[xm] * wy0 + r1[xm] * fy;
    const float ac = r0[jb] * wy0 + r1[jb] * fy;
    const float ap = r0[xp] * wy0 + r1[xp] * fy;

    float4 o;
    o.x = 0.375f * am + 0.625f * ac;
    o.y = 0.125f * am + 0.875f * ac;
    o.z = 0.875f * ac + 0.125f * ap;
    o.w = 0.625f * ac + 0.375f * ap;
    ((float4*)outp)[gid] = o;
}

// ---------------------------------------------------------------------------
extern "C" void kernel_launch(void* const* d_in, const int* in_sizes, int n_in,
                              void* d_out, int out_size, void* d_ws, size_t ws_size,
                              hipStream_t stream)
{
    const float* feats  = (const float*)d_in[0];   // [4][256][16384]
    const float* seed_w = (const float*)d_in[1];   // [16][256] (first 8 rows)
    const float* seed_b = (const float*)d_in[2];   // [16]
    // d_in[3]: k (int) — fixed at 8 by setup_inputs; grid shapes hardcoded.

    float* out        = (float*)d_out;
    float* probs_full = out;                        // 4*8*512*512 = 8388608
    float* proto_out  = out + 8388608;              // 4*8*256     = 8192
    float* logits_out = out + 8388608 + 8192;       // 4*8*128*128 = 524288

    // part_num (8 MB) lives in the probs_full region of d_out: fully consumed
    // by skm_reduce before skm_upsample overwrites the region last.
    float* part_num = probs_full;                   // 4*256*8*256 = 2097152 floats

    float* ws       = (float*)d_ws;
    float* fsq      = ws;                           // 65536
    float* part_den = ws + 65536;                   // 4*256*8 = 8192
    float* proto_t  = part_den + 8192;              // 4*256*8 = 8192
    float* psq_ws   = proto_t + 8192;               // 32
    float* probs_ws = psq_ws + 32;                  // 524288  (total ~2.4 MB)

    const dim3 pg(BB * NBLK), pb(512);
    const dim3 rg(32), rb(1024);

    // seed pass + initial proto
    skm_pass<0><<<pg, pb, 0, stream>>>(feats, seed_w, seed_b, proto_t, psq_ws,
                                       fsq, part_num, part_den, nullptr, nullptr);
    skm_reduce<<<rg, rb, 0, stream>>>(part_num, part_den, proto_t, psq_ws, nullptr);
    // cluster iterations 1,2
    skm_pass<1><<<pg, pb, 0, stream>>>(feats, seed_w, seed_b, proto_t, psq_ws,
                                       fsq, part_num, part_den, nullptr, nullptr);
    skm_reduce<<<rg, rb, 0, stream>>>(part_num, part_den, proto_t, psq_ws, nullptr);
    skm_pass<1><<<pg, pb, 0, stream>>>(feats, seed_w, seed_b, proto_t, psq_ws,
                                       fsq, part_num, part_den, nullptr, nullptr);
    skm_reduce<<<rg, rb, 0, stream>>>(part_num, part_den, proto_t, psq_ws, nullptr);
    // iteration 3: emit logits_map + probs(=assign), final proto -> d_out
    skm_pass<2><<<pg, pb, 0, stream>>>(feats, seed_w, seed_b, proto_t, psq_ws,
                                       fsq, part_num, part_den, logits_out, probs_ws);
    skm_reduce<<<rg, rb, 0, stream>>>(part_num, part_den, proto_t, psq_ws, proto_out);
    // upsample x4 (overwrites part_num region with final probs)
    skm_upsample<<<dim3(8192), dim3(256), 0, stream>>>(probs_ws, probs_full);
}